// Round 3
// baseline (467.369 us; speedup 1.0000x reference)
//
#include <hip/hip_runtime.h>

// SparseJL: out[n,o] = sum_k x[n,k] * Phi[o,k]
// x: (16384, 4096) fp32, Phi: (1024, 4096) fp32, s=10 nnz per COLUMN (~1% dense).
// R3: counting-sorted column->thread assignment (equalize per-wave trip count),
//     paired ELL entries (int4 = 2 taps per global load), v_pk_fma_f32 via
//     float2 math, LDS-shuffled coalesced output stores.
// Note: dur_us carries ~280 us of fixed harness overhead (1 GB d_ws re-poison
// at ~160 us + d_in restore); only jl_main + preproc are controllable.

#define IN_DIM 4096
#define OUT_DIM 1024
#define NROWS 16384
#define RPB 8                 // rows of x per block (8 bf16 = one uint4 per k)
#define MAXP 48               // entry PAIRS per column
#define MAXNZ (2 * MAXP)      // nnz/row: mean 40, sigma 6.3 -> 92 is ~8 sigma

typedef float f2 __attribute__((ext_vector_type(2)));

__device__ __forceinline__ unsigned bf16_rne(float f) {
    unsigned u = __float_as_uint(f);
    return (u + 0x7fffu + ((u >> 16) & 1u)) >> 16;
}
__device__ __forceinline__ unsigned pack2(float lo, float hi) {
    return bf16_rne(lo) | (bf16_rne(hi) << 16);
}
__device__ __forceinline__ float blo(unsigned d) { return __uint_as_float(d << 16); }
__device__ __forceinline__ float bhi(unsigned d) { return __uint_as_float(d & 0xffff0000u); }

// ---------------------------------------------------------------------------
// Kernel 1: dense Phi -> paired j-major ELL.
// Pair p of column o lives at int4 ent2[p*OUT_DIM + o] = {k0,v0,k1,v1}:
// lanes (consecutive o) load consecutive 16B -> perfectly coalesced.
// 4 zero sentinels after c cover pair rounding + the jp+1 prefetch.
// ---------------------------------------------------------------------------
__global__ __launch_bounds__(256) void build_sparse(const float* __restrict__ Phi,
                                                    int* __restrict__ cnt,
                                                    int2* __restrict__ ent) {
    const int o = blockIdx.x;
    __shared__ int lcnt;
    if (threadIdx.x == 0) lcnt = 0;
    __syncthreads();
    const float* row = Phi + (size_t)o * IN_DIM;
    for (int k = threadIdx.x; k < IN_DIM; k += 256) {
        float v = row[k];
        if (v != 0.0f) {
            int p = atomicAdd(&lcnt, 1);
            if (p < MAXNZ - 4) {
                // int4 ent2[pair][OUT_DIM] viewed as int2: ((pair*OUT_DIM+o)*2 + half)
                ent[(((size_t)(p >> 1)) * OUT_DIM + o) * 2 + (p & 1)] =
                    make_int2(k, __float_as_int(v));
            }
        }
    }
    __syncthreads();
    int c = lcnt;
    if (c > MAXNZ - 4) c = MAXNZ - 4;
    if (threadIdx.x < 4) {
        int j = c + threadIdx.x;
        ent[(((size_t)(j >> 1)) * OUT_DIM + o) * 2 + (j & 1)] = make_int2(0, 0);
    }
    if (threadIdx.x == 0) cnt[o] = c;
}

// ---------------------------------------------------------------------------
// Kernel 2: counting sort of the 1024 columns by cnt -> perm[rank] = o.
// Waves in jl_main then get near-equal trip counts (kills lane divergence).
// ---------------------------------------------------------------------------
__global__ __launch_bounds__(1024) void sort_cols(const int* __restrict__ cnt,
                                                  int* __restrict__ perm) {
    __shared__ int hist[128];
    __shared__ int base[128];
    const int tid = threadIdx.x;
    if (tid < 128) hist[tid] = 0;
    __syncthreads();
    const int c = cnt[tid] & 127;
    atomicAdd(&hist[c], 1);
    __syncthreads();
    if (tid == 0) {
        int run = 0;
        for (int i = 0; i < 128; ++i) { base[i] = run; run += hist[i]; }
    }
    __syncthreads();
    int pos = atomicAdd(&base[c], 1);
    perm[pos] = tid;
}

// ---------------------------------------------------------------------------
// Kernel 3: sparse JL product. One block = 8 rows of x, 1024 threads,
// 64 KB LDS -> 2 blocks/CU = 32 waves/CU. Thread owns column perm[tid].
// Inner loop per PAIR of taps: 1 global_load_dwordx4 (ent, L2-resident),
// 2 ds_read_b128 (packed bf16 x), 8 v_pk_fma_f32.
// Output goes through LDS so global stores stay coalesced despite perm.
// ---------------------------------------------------------------------------
__global__ __launch_bounds__(1024, 8) void jl_main(const float* __restrict__ x,
                                                   const int* __restrict__ cnt,
                                                   const int* __restrict__ perm,
                                                   const int4* __restrict__ ent,
                                                   float* __restrict__ out) {
    __shared__ uint4 xt[IN_DIM];  // 64 KB; reused as float sout[8][1024] after
    const int tid = threadIdx.x;
    const size_t n0 = (size_t)blockIdx.x * RPB;
    const float* xr = x + n0 * IN_DIM;

    // ---- stage: k = tid + i*1024 -> lane-contiguous ds_write_b128 (no conflict)
#pragma unroll
    for (int i = 0; i < IN_DIM / 1024; ++i) {
        const int k = tid + i * 1024;
        float r0 = xr[k];
        float r1 = xr[1 * IN_DIM + k];
        float r2 = xr[2 * IN_DIM + k];
        float r3 = xr[3 * IN_DIM + k];
        float r4 = xr[4 * IN_DIM + k];
        float r5 = xr[5 * IN_DIM + k];
        float r6 = xr[6 * IN_DIM + k];
        float r7 = xr[7 * IN_DIM + k];
        uint4 w;
        w.x = pack2(r0, r1);
        w.y = pack2(r2, r3);
        w.z = pack2(r4, r5);
        w.w = pack2(r6, r7);
        xt[k] = w;
    }
    __syncthreads();

    // ---- compute
    const int o = perm[tid];
    const int pairs = (cnt[o] + 1) >> 1;
    const int4* ep = ent + o;

    f2 a0 = {0.f, 0.f}, a1 = {0.f, 0.f}, a2 = {0.f, 0.f}, a3 = {0.f, 0.f};
    int4 e = ep[0];  // sentinel-safe even if pairs == 0
    for (int jp = 0; jp < pairs; ++jp) {
        int4 en = ep[(size_t)(jp + 1) * OUT_DIM];  // prefetch next pair (L2)
        uint4 xa = xt[e.x];
        uint4 xb = xt[e.z];
        float va = __int_as_float(e.y);
        float vb = __int_as_float(e.w);
        f2 vva = {va, va};
        f2 vvb = {vb, vb};
        f2 p0 = {blo(xa.x), bhi(xa.x)};
        f2 p1 = {blo(xa.y), bhi(xa.y)};
        f2 p2 = {blo(xa.z), bhi(xa.z)};
        f2 p3 = {blo(xa.w), bhi(xa.w)};
        a0 += vva * p0;   // fp-contract -> v_pk_fma_f32
        a1 += vva * p1;
        a2 += vva * p2;
        a3 += vva * p3;
        f2 q0 = {blo(xb.x), bhi(xb.x)};
        f2 q1 = {blo(xb.y), bhi(xb.y)};
        f2 q2 = {blo(xb.z), bhi(xb.z)};
        f2 q3 = {blo(xb.w), bhi(xb.w)};
        a0 += vvb * q0;
        a1 += vvb * q1;
        a2 += vvb * q2;
        a3 += vvb * q3;
        e = en;
    }

    // ---- epilogue: LDS shuffle so global stores are coalesced despite perm
    __syncthreads();                 // all xt reads complete before overwrite
    float* sout = (float*)xt;        // [8][OUT_DIM]
    sout[0 * OUT_DIM + o] = a0.x;
    sout[1 * OUT_DIM + o] = a0.y;
    sout[2 * OUT_DIM + o] = a1.x;
    sout[3 * OUT_DIM + o] = a1.y;
    sout[4 * OUT_DIM + o] = a2.x;
    sout[5 * OUT_DIM + o] = a2.y;
    sout[6 * OUT_DIM + o] = a3.x;
    sout[7 * OUT_DIM + o] = a3.y;
    __syncthreads();
    float* op = out + n0 * OUT_DIM + tid;
#pragma unroll
    for (int r = 0; r < RPB; ++r)
        op[(size_t)r * OUT_DIM] = sout[r * OUT_DIM + tid];
}

extern "C" void kernel_launch(void* const* d_in, const int* in_sizes, int n_in,
                              void* d_out, int out_size, void* d_ws, size_t ws_size,
                              hipStream_t stream) {
    const float* x   = (const float*)d_in[0];   // 16384 x 4096
    const float* Phi = (const float*)d_in[1];   // 1024 x 4096
    float* out = (float*)d_out;                 // 16384 x 1024

    // ws: [cnt 4KB][perm 4KB][ent2 48*1024*16B = 768KB]
    int*  cnt  = (int*)d_ws;
    int*  perm = (int*)((char*)d_ws + OUT_DIM * sizeof(int));
    int2* ent  = (int2*)((char*)d_ws + 2 * OUT_DIM * sizeof(int));

    build_sparse<<<OUT_DIM, 256, 0, stream>>>(Phi, cnt, ent);
    sort_cols<<<1, 1024, 0, stream>>>(cnt, perm);
    jl_main<<<NROWS / RPB, 1024, 0, stream>>>(x, cnt, perm, (const int4*)ent, out);
}